// Round 4
// baseline (229.881 us; speedup 1.0000x reference)
//
#include <hip/hip_runtime.h>

#define BINS 128
#define FEAT 64
#define SEG (BINS * FEAT)   // 8192 counters per b-histogram
#define B_DIM 32
#define S_DIM 16384
#define CHUNKS 16           // blocks per batch -> 512 blocks = 2/CU
#define THREADS 512         // 8 waves
#define UNROLL 8
#define PAIRS (SEG / 2)     // u16-packed partial: 4096 u32 per (b,chunk)

// ---------------- Fused path: hist + last-block-per-b reduction ----------------
// grid = (CHUNKS, B_DIM). Each block builds an LDS u32 histogram of its
// 1024-row chunk, stores it as u16 pairs (max count/block = 1024 < 2^16,
// halves partial traffic vs u32), then signals a per-b arrival counter.
// The LAST block of each b reduces that b's 16 partials and writes the
// weighted output — no second kernel launch, and per-b reduction overlaps
// the remaining hist work of other batches.
// Cross-XCD visibility: syncthreads drains vmcnt (stores reach XCD L2);
// release = __threadfence (agent fence -> L2 writeback) before the
// device-scope atomicAdd; acquire = __threadfence after observing count==15
// (invalidates L1/L2) before reading other blocks' partials. This is the
// standard rocPRIM decoupled-completion pattern.
__global__ __launch_bounds__(THREADS, 2)
void hist_fused(const float* __restrict__ x, unsigned* __restrict__ part32,
                unsigned* __restrict__ counters, float* __restrict__ out,
                const float* __restrict__ w) {
    __shared__ unsigned hist[SEG];
    uint4* h4 = (uint4*)hist;
    for (int i = threadIdx.x; i < SEG / 4; i += THREADS)
        h4[i] = make_uint4(0u, 0u, 0u, 0u);
    __syncthreads();

    const int b    = blockIdx.y;
    const int lane = threadIdx.x & 63;
    const int wave = threadIdx.x >> 6;                 // 0..7
    const int chunk = S_DIM / CHUNKS;                  // 1024 rows per block
    const int rows_per_wave = chunk / (THREADS / 64);  // 128

    const float* xb = x + (size_t)b * S_DIM * FEAT;
    const int s0 = blockIdx.x * chunk + wave * rows_per_wave;

    for (int it = 0; it < rows_per_wave; it += UNROLL) {
        float v[UNROLL];
        #pragma unroll
        for (int u = 0; u < UNROLL; ++u)
            v[u] = __builtin_nontemporal_load(
                       &xb[(size_t)(s0 + it + u) * FEAT + lane]);  // coalesced 256B/wave
        #pragma unroll
        for (int u = 0; u < UNROLL; ++u) {
            int bin = (int)(v[u] * 128.0f);            // exact trunc like ref
            bin = bin < 0 ? 0 : (bin > 127 ? 127 : bin);
            // addr = bin*64 + lane -> distinct addr/lane, bank = lane%32 (free 2-way)
            atomicAdd(&hist[(bin << 6) + lane], 1u);   // ds_add_u32
        }
    }
    __syncthreads();

    // Pack u32 counts into u16 pairs; plain stores keep partials L2-resident.
    unsigned* p = part32 + ((size_t)(b * CHUNKS + blockIdx.x)) * PAIRS;
    for (int i = threadIdx.x; i < PAIRS; i += THREADS) {
        unsigned lo = hist[2 * i], hi = hist[2 * i + 1];
        p[i] = lo | (hi << 16);
    }

    // ---- completion protocol ----
    __shared__ unsigned is_last;
    __syncthreads();                       // all partial stores drained (vmcnt 0)
    if (threadIdx.x == 0) {
        __threadfence();                   // release: writeback this XCD's L2
        unsigned old = atomicAdd(&counters[b], 1u);    // device-scope
        is_last = (old == CHUNKS - 1) ? 1u : 0u;
    }
    __syncthreads();
    if (!is_last) return;

    __threadfence();                       // acquire: invalidate stale cache lines

    // ---- last block for this b: reduce 16 partials, apply weights ----
    const unsigned* pb = part32 + (size_t)b * CHUNKS * PAIRS;
    const int t = threadIdx.x;             // thread t owns pairs t*8 .. t*8+7
    unsigned slo[8] = {0, 0, 0, 0, 0, 0, 0, 0};
    unsigned shi[8] = {0, 0, 0, 0, 0, 0, 0, 0};
    for (int c = 0; c < CHUNKS; ++c) {
        const uint4* q = (const uint4*)(pb + (size_t)c * PAIRS + t * 8);
        uint4 a = q[0], d = q[1];
        unsigned vv[8] = {a.x, a.y, a.z, a.w, d.x, d.y, d.z, d.w};
        #pragma unroll
        for (int j = 0; j < 8; ++j) {
            slo[j] += vv[j] & 0xFFFFu;
            shi[j] += vv[j] >> 16;
        }
    }
    // thread t writes floats [t*16, t*16+16) of out[b]; float4 stores.
    const float4* w4 = (const float4*)(w + t * 16);
    float4* o4 = (float4*)(out + (size_t)b * SEG + t * 16);
    #pragma unroll
    for (int k = 0; k < 4; ++k) {
        float4 wv = w4[k];
        float4 o;
        o.x = (float)slo[2 * k]     * wv.x;
        o.y = (float)shi[2 * k]     * wv.y;
        o.z = (float)slo[2 * k + 1] * wv.z;
        o.w = (float)shi[2 * k + 1] * wv.w;
        o4[k] = o;                         // overwrites poison
    }
}

// ---------------- Fallback path (ws too small): global-atomic version ----------------

__global__ __launch_bounds__(THREADS, 2)
void hist_kernel(const float* __restrict__ x, unsigned* out) {
    __shared__ unsigned hist[SEG];
    for (int i = threadIdx.x; i < SEG; i += THREADS) hist[i] = 0u;
    __syncthreads();

    const int b    = blockIdx.y;
    const int lane = threadIdx.x & 63;
    const int wave = threadIdx.x >> 6;
    const int chunk = S_DIM / CHUNKS;
    const int rows_per_wave = chunk / (THREADS / 64);

    const float* xb = x + (size_t)b * S_DIM * FEAT;
    const int s0 = blockIdx.x * chunk + wave * rows_per_wave;

    for (int it = 0; it < rows_per_wave; it += UNROLL) {
        float v[UNROLL];
        #pragma unroll
        for (int u = 0; u < UNROLL; ++u)
            v[u] = xb[(size_t)(s0 + it + u) * FEAT + lane];
        #pragma unroll
        for (int u = 0; u < UNROLL; ++u) {
            int bin = (int)(v[u] * 128.0f);
            bin = bin < 0 ? 0 : (bin > 127 ? 127 : bin);
            atomicAdd(&hist[(bin << 6) + lane], 1u);
        }
    }
    __syncthreads();

    unsigned* gout = out + (size_t)b * SEG;
    for (int i = threadIdx.x; i < SEG; i += THREADS) {
        unsigned c = hist[i];
        if (c) atomicAdd(&gout[i], c);
    }
}

__global__ void finalize_kernel(const unsigned* cnt, float* out,
                                const float* __restrict__ w, int n) {
    int i = blockIdx.x * blockDim.x + threadIdx.x;
    if (i < n) {
        unsigned c = cnt[i];
        out[i] = (float)c * w[i & (SEG - 1)];
    }
}

extern "C" void kernel_launch(void* const* d_in, const int* in_sizes, int n_in,
                              void* d_out, int out_size, void* d_ws, size_t ws_size,
                              hipStream_t stream) {
    const float* x = (const float*)d_in[0];
    const float* w = (const float*)d_in[1];
    float* out = (float*)d_out;

    const size_t part_bytes = (size_t)B_DIM * CHUNKS * PAIRS * sizeof(unsigned); // 8 MiB
    const size_t ws_needed  = part_bytes + 128;       // + 32 u32 counters

    if (ws_size >= ws_needed && d_ws != nullptr) {
        unsigned* part32   = (unsigned*)d_ws;
        unsigned* counters = (unsigned*)((char*)d_ws + part_bytes);
        // zero the 32 arrival counters (ws is poisoned each call); capturable.
        hipMemsetAsync(counters, 0, B_DIM * sizeof(unsigned), stream);
        dim3 grid(CHUNKS, B_DIM);
        hist_fused<<<grid, THREADS, 0, stream>>>(x, part32, counters, out, w);
    } else {
        // Fallback: old path with global atomic merge.
        hipMemsetAsync(d_out, 0, (size_t)out_size * sizeof(float), stream);
        dim3 grid(CHUNKS, B_DIM);
        hist_kernel<<<grid, THREADS, 0, stream>>>(x, (unsigned*)d_out);
        int n = out_size;
        finalize_kernel<<<(n + 255) / 256, 256, 0, stream>>>((const unsigned*)d_out, out, w, n);
    }
}

// Round 5
// 190.594 us; speedup vs baseline: 1.2061x; 1.2061x over previous
//
#include <hip/hip_runtime.h>

#define BINS 128
#define FEAT 64
#define SEG (BINS * FEAT)   // 8192 counters per b-histogram
#define B_DIM 32
#define S_DIM 16384
#define CHUNKS 16           // blocks per batch -> 512 blocks = 2/CU
#define THREADS 512         // 8 waves
#define UNROLL 8
#define PAIRS (SEG / 2)     // u16-packed partial: 4096 u32 per (b,chunk)

// ---------------- Primary path: split hist -> reduce, u16-packed partials --------
// Round-4 lesson: fusing via last-block-done + __threadfence costs ~55us
// (agent-scope fences force per-XCD L2 writeback/invalidate, serializing the
// memory system: hist_fused ran at 11% HBM peak). The ~3us launch gap of the
// split structure is far cheaper. KEEP TWO KERNELS.
// Packing kept from round 4: per-block counts <= 1024 and per-b sums <= 16384,
// so u16 pairs packed in u32 never carry -> partial traffic halves (16->8 MiB).

__global__ __launch_bounds__(THREADS, 2)
void hist_part(const float* __restrict__ x, unsigned* __restrict__ part) {
    __shared__ unsigned hist[SEG];
    uint4* h4 = (uint4*)hist;
    for (int i = threadIdx.x; i < SEG / 4; i += THREADS)
        h4[i] = make_uint4(0u, 0u, 0u, 0u);
    __syncthreads();

    const int b    = blockIdx.y;
    const int lane = threadIdx.x & 63;
    const int wave = threadIdx.x >> 6;                 // 0..7
    const int chunk = S_DIM / CHUNKS;                  // 1024 rows per block
    const int rows_per_wave = chunk / (THREADS / 64);  // 128

    const float* xb = x + (size_t)b * S_DIM * FEAT;
    const int s0 = blockIdx.x * chunk + wave * rows_per_wave;

    for (int it = 0; it < rows_per_wave; it += UNROLL) {
        float v[UNROLL];
        #pragma unroll
        for (int u = 0; u < UNROLL; ++u)
            v[u] = __builtin_nontemporal_load(
                       &xb[(size_t)(s0 + it + u) * FEAT + lane]);  // coalesced 256B/wave
        #pragma unroll
        for (int u = 0; u < UNROLL; ++u) {
            int bin = (int)(v[u] * 128.0f);            // exact trunc like ref
            bin = bin < 0 ? 0 : (bin > 127 ? 127 : bin);
            // addr = bin*64 + lane -> distinct addr/lane, bank = lane%32 (free 2-way)
            atomicAdd(&hist[(bin << 6) + lane], 1u);   // ds_add_u32
        }
    }
    __syncthreads();

    // u16-pack: counts <= 1024, no masking needed. Plain stores -> L2-resident.
    unsigned* p = part + ((size_t)(b * CHUNKS + blockIdx.x)) * PAIRS;
    for (int i = threadIdx.x; i < PAIRS; i += THREADS)
        p[i] = hist[2 * i] | (hist[2 * i + 1] << 16);
}

// out[b][q*8 .. q*8+7] = (sum_c packed partials) * w; uint4 loads, float4 stores.
__global__ __launch_bounds__(256)
void reduce_fin(const unsigned* __restrict__ part, float* __restrict__ out,
                const float* __restrict__ w) {
    int t = blockIdx.x * blockDim.x + threadIdx.x;     // 0 .. B*PAIRS/4-1 (=32768)
    if (t >= B_DIM * (PAIRS / 4)) return;
    int b = t >> 10;                                   // PAIRS/4 = 1024 uint4 per seg
    int q = t & 1023;
    const uint4* base = (const uint4*)(part + (size_t)b * CHUNKS * PAIRS) + q;
    unsigned s[8] = {0, 0, 0, 0, 0, 0, 0, 0};
    #pragma unroll
    for (int c = 0; c < CHUNKS; ++c) {
        uint4 v = base[(size_t)c * (PAIRS / 4)];
        s[0] += v.x & 0xFFFFu;  s[1] += v.x >> 16;     // sums <= 16384, no carry
        s[2] += v.y & 0xFFFFu;  s[3] += v.y >> 16;
        s[4] += v.z & 0xFFFFu;  s[5] += v.z >> 16;
        s[6] += v.w & 0xFFFFu;  s[7] += v.w >> 16;
    }
    const float4* w4 = (const float4*)(w + q * 8);     // weight idx = out idx mod SEG
    float4* o4 = (float4*)(out + (size_t)b * SEG + (size_t)q * 8);
    float4 w0 = w4[0], w1 = w4[1];
    float4 o0, o1;
    o0.x = (float)s[0] * w0.x;  o0.y = (float)s[1] * w0.y;
    o0.z = (float)s[2] * w0.z;  o0.w = (float)s[3] * w0.w;
    o1.x = (float)s[4] * w1.x;  o1.y = (float)s[5] * w1.y;
    o1.z = (float)s[6] * w1.z;  o1.w = (float)s[7] * w1.w;
    o4[0] = o0;                                        // overwrites poison
    o4[1] = o1;
}

// ---------------- Fallback path (ws too small): global-atomic version ------------

__global__ __launch_bounds__(THREADS, 2)
void hist_kernel(const float* __restrict__ x, unsigned* out) {
    __shared__ unsigned hist[SEG];
    for (int i = threadIdx.x; i < SEG; i += THREADS) hist[i] = 0u;
    __syncthreads();

    const int b    = blockIdx.y;
    const int lane = threadIdx.x & 63;
    const int wave = threadIdx.x >> 6;
    const int chunk = S_DIM / CHUNKS;
    const int rows_per_wave = chunk / (THREADS / 64);

    const float* xb = x + (size_t)b * S_DIM * FEAT;
    const int s0 = blockIdx.x * chunk + wave * rows_per_wave;

    for (int it = 0; it < rows_per_wave; it += UNROLL) {
        float v[UNROLL];
        #pragma unroll
        for (int u = 0; u < UNROLL; ++u)
            v[u] = xb[(size_t)(s0 + it + u) * FEAT + lane];
        #pragma unroll
        for (int u = 0; u < UNROLL; ++u) {
            int bin = (int)(v[u] * 128.0f);
            bin = bin < 0 ? 0 : (bin > 127 ? 127 : bin);
            atomicAdd(&hist[(bin << 6) + lane], 1u);
        }
    }
    __syncthreads();

    unsigned* gout = out + (size_t)b * SEG;
    for (int i = threadIdx.x; i < SEG; i += THREADS) {
        unsigned c = hist[i];
        if (c) atomicAdd(&gout[i], c);
    }
}

__global__ void finalize_kernel(const unsigned* cnt, float* out,
                                const float* __restrict__ w, int n) {
    int i = blockIdx.x * blockDim.x + threadIdx.x;
    if (i < n) {
        unsigned c = cnt[i];
        out[i] = (float)c * w[i & (SEG - 1)];
    }
}

extern "C" void kernel_launch(void* const* d_in, const int* in_sizes, int n_in,
                              void* d_out, int out_size, void* d_ws, size_t ws_size,
                              hipStream_t stream) {
    const float* x = (const float*)d_in[0];
    const float* w = (const float*)d_in[1];
    float* out = (float*)d_out;

    const size_t ws_needed = (size_t)B_DIM * CHUNKS * PAIRS * sizeof(unsigned); // 8 MiB

    if (ws_size >= ws_needed && d_ws != nullptr) {
        unsigned* part = (unsigned*)d_ws;
        dim3 grid(CHUNKS, B_DIM);
        hist_part<<<grid, THREADS, 0, stream>>>(x, part);
        int nt = B_DIM * (PAIRS / 4);                  // 32768 threads
        reduce_fin<<<(nt + 255) / 256, 256, 0, stream>>>(part, out, w);
    } else {
        // Fallback: old path with global atomic merge.
        hipMemsetAsync(d_out, 0, (size_t)out_size * sizeof(float), stream);
        dim3 grid(CHUNKS, B_DIM);
        hist_kernel<<<grid, THREADS, 0, stream>>>(x, (unsigned*)d_out);
        int n = out_size;
        finalize_kernel<<<(n + 255) / 256, 256, 0, stream>>>((const unsigned*)d_out, out, w, n);
    }
}